// Round 5
// baseline (308.383 us; speedup 1.0000x reference)
//
#include <hip/hip_runtime.h>
#include <cstddef>

#define Bn 128
#define Pn 8732
#define Cn 21
#define On 16
#define MAGIC 0x13579BDFu

__device__ __forceinline__ void argmax_combine(float& v, int& p, float v2, int p2) {
  if (v2 > v || (v2 == v && p2 < p)) { v = v2; p = p2; }
}

// ---------------------------------------------------------------------------
// One block per image (128 blocks x 1024 thr, 1 block/CU via ~150KB LDS).
// Phase B: 16 waves stream 137 chunks of 64 priors; register ping-pong
//   prefetch hides HBM latency behind softmax+IoU compute; ce0/bti -> LDS.
// Phase C: forced matches, losses (ce_neg in registers).
// Phase D: exact radix top-k with parallel shuffle suffix-scan.
// Phase E: atomicExch+flag handoff; block 0 finalizes (no extra node).
// ---------------------------------------------------------------------------
__global__ __launch_bounds__(1024) void fused_kernel(
    const float* __restrict__ loc, const float* __restrict__ conf,
    const float* __restrict__ dbox, const float* __restrict__ targets,
    unsigned int* __restrict__ res, float* __restrict__ out) {
  const int b = blockIdx.x;
  const int tid = threadIdx.x;
  const int wv = tid >> 6, lane = tid & 63;

  __shared__ float s_ce[Pn];              // ce0 per prior
  __shared__ float s_stage[16][1344];     // per-wave staging (5376 B each)
  __shared__ unsigned char s_bti[Pn];     // bti | pos<<4
  __shared__ unsigned hist[16][256];
  __shared__ float s_tt[80];
  __shared__ float s_ar[On];
  __shared__ float s_mv[On][16];
  __shared__ int   s_mp[On][16];
  __shared__ int   s_bp[On];
  __shared__ float s_redf[2][16];
  __shared__ int   s_redi[16];
  __shared__ int   s_sfx[256];
  __shared__ int   s_wsum[4];
  __shared__ unsigned s_prefix;
  __shared__ int s_kk, s_np;

  if (tid < 80) s_tt[tid] = targets[b * 80 + tid];   // 1024 threads: covers all 80
  __syncthreads();
  if (tid < On)
    s_ar[tid] = (s_tt[tid*5+2] - s_tt[tid*5+0]) * (s_tt[tid*5+3] - s_tt[tid*5+1]);
  __syncthreads();

  // ---- Phase B: stream conf (chunks ci = wv + 16*i), prefetch-pipelined ----
  float bestv[On]; int bestp[On];
  #pragma unroll
  for (int j = 0; j < On; j++) { bestv[j] = -1.0f; bestp[j] = 0x7fffffff; }

  const size_t confBase = (size_t)b * Pn * Cn;
  const int nch = (136 - wv) / 16 + 1;               // 9 or 8 chunks
  float4 rg[2][6];

  auto load_chunk = [&](float4 (&r)[6], int ci) {
    const int n4 = (ci == 136) ? 147 : 336;          // rows*21/4
    const float4* src = (const float4*)(conf + confBase + (size_t)ci * 64 * Cn);
    #pragma unroll
    for (int q = 0; q < 6; q++)
      if (lane + 64*q < n4) r[q] = src[lane + 64*q];
  };

  load_chunk(rg[0], wv);
  for (int i = 0; i < nch; i++) {
    const int ci = wv + 16 * i;
    const int n4 = (ci == 136) ? 147 : 336;
    const int rows = (ci == 136) ? 28 : 64;
    float4 (&cur)[6] = rg[i & 1];
    {
      float4* dst = (float4*)s_stage[wv];
      #pragma unroll
      for (int q = 0; q < 6; q++)
        if (lane + 64*q < n4) dst[lane + 64*q] = cur[q];
    }
    if (i + 1 < nch) load_chunk(rg[(i + 1) & 1], ci + 16);   // overlaps compute

    if (lane < rows) {
      const int p = ci * 64 + lane;
      const float* x = s_stage[wv] + lane * Cn;      // stride-21: 2-way, free
      float m = x[0];
      #pragma unroll
      for (int q = 1; q < Cn; q++) m = fmaxf(m, x[q]);
      float s = 0.0f;
      #pragma unroll
      for (int q = 0; q < Cn; q++) s += expf(x[q] - m);
      float lse = m + logf(s);
      s_ce[p] = lse - x[0];                          // >= 0 always

      float4 d = ((const float4*)dbox)[p];
      float px1 = d.x - d.z * 0.5f, py1 = d.y - d.w * 0.5f;
      float px2 = d.x + d.z * 0.5f, py2 = d.y + d.w * 0.5f;
      float ap = d.z * d.w;
      float mv = -1.0f; int mj = 0;
      #pragma unroll
      for (int j = 0; j < On; j++) {
        float lx = fmaxf(s_tt[j*5+0], px1);
        float ly = fmaxf(s_tt[j*5+1], py1);
        float rx = fminf(s_tt[j*5+2], px2);
        float ry = fminf(s_tt[j*5+3], py2);
        float w = fmaxf(rx - lx, 0.0f), h = fmaxf(ry - ly, 0.0f);
        float inter = w * h;
        float ov = inter / (s_ar[j] + ap - inter);
        if (ov > bestv[j]) { bestv[j] = ov; bestp[j] = p; }  // smallest p kept
        if (ov > mv) { mv = ov; mj = j; }                    // first max over j
      }
      s_bti[p] = (unsigned char)(mj | ((mv >= 0.5f) ? 16 : 0));
    }
  }

  // per-truth argmax: wave reduce -> LDS -> combine -> forced overwrites
  #pragma unroll
  for (int j = 0; j < On; j++) {
    float v = bestv[j]; int p = bestp[j];
    #pragma unroll
    for (int off = 32; off; off >>= 1) {
      float v2 = __shfl_down(v, off);
      int p2 = __shfl_down(p, off);
      argmax_combine(v, p, v2, p2);
    }
    if (lane == 0) { s_mv[j][wv] = v; s_mp[j][wv] = p; }
  }
  __syncthreads();
  if (tid < On) {
    float v = s_mv[tid][0]; int p = s_mp[tid][0];
    #pragma unroll
    for (int w = 1; w < 16; w++) argmax_combine(v, p, s_mv[tid][w], s_mp[tid][w]);
    s_bp[tid] = p;
  }
  __syncthreads();
  if (tid == 0) {
    #pragma unroll
    for (int j = 0; j < On; j++)                 // ascending: last j wins
      s_bti[s_bp[j]] = (unsigned char)(j | 16);
  }
  __syncthreads();

  // ---- Phase C: ce_neg to registers, np count, positive losses ----
  float ce_r[9];
  float my_loc = 0.0f, my_cep = 0.0f; int my_np = 0;
  #pragma unroll
  for (int s9 = 0; s9 < 9; s9++) {
    ce_r[s9] = 0.0f;
    const int p = tid + 1024 * s9;
    if (p < Pn) {
      int pk = s_bti[p];
      float c0 = s_ce[p];
      int pos = pk >> 4, bt = pk & 15;
      ce_r[s9] = pos ? 0.0f : c0;
      if (pos) {
        my_np++;
        const float* t = &s_tt[bt * 5];
        int c = (int)t[4] + 1;
        const float* row = conf + confBase + (size_t)p * Cn;
        my_cep += c0 + row[0] - row[c];            // lse - x[c]
        float4 d = ((const float4*)dbox)[p];
        float mx1 = t[0], my1 = t[1], mx2 = t[2], my2 = t[3];
        float g0 = ((mx1 + mx2) * 0.5f - d.x) / (0.1f * d.z);
        float g1 = ((my1 + my2) * 0.5f - d.y) / (0.1f * d.w);
        float g2 = logf((mx2 - mx1) / d.z) / 0.2f;
        float g3 = logf((my2 - my1) / d.w) / 0.2f;
        float4 ld = ((const float4*)loc)[(size_t)b * Pn + p];
        float g[4] = {g0, g1, g2, g3};
        float l[4] = {ld.x, ld.y, ld.z, ld.w};
        #pragma unroll
        for (int q = 0; q < 4; q++) {
          float ad = fabsf(l[q] - g[q]);
          my_loc += (ad < 1.0f) ? 0.5f * ad * ad : ad - 0.5f;
        }
      }
    }
  }
  {
    int np = my_np;
    #pragma unroll
    for (int off = 32; off; off >>= 1) np += __shfl_down(np, off);
    if (lane == 0) s_redi[wv] = np;
  }
  __syncthreads();
  if (tid == 0) {
    int np = 0;
    #pragma unroll
    for (int w = 0; w < 16; w++) np += s_redi[w];
    s_np = np;
  }
  __syncthreads();

  // ---- Phase D: exact k-th largest via radix select + parallel suffix scan
  const int k = min(s_np * 3, Pn);
  int kk = max(k, 1);                       // kk=1 degenerate: T=max, sel=0
  unsigned prefix = 0, maskb = 0;
  for (int shift = 24; shift >= 0; shift -= 8) {
    #pragma unroll
    for (int j = 0; j < 4; j++) hist[wv][lane * 4 + j] = 0;
    __syncthreads();
    #pragma unroll
    for (int s9 = 0; s9 < 9; s9++) {
      const int p = tid + 1024 * s9;
      if (p < Pn) {
        unsigned u = __float_as_uint(ce_r[s9]);
        if ((u & maskb) == prefix) atomicAdd(&hist[wv][(u >> shift) & 255u], 1u);
      }
    }
    __syncthreads();
    int v = 0;
    if (tid < 256) {
      int h = 0;
      #pragma unroll
      for (int w = 0; w < 16; w++) h += (int)hist[w][tid];
      v = h;
      #pragma unroll
      for (int off = 1; off < 64; off <<= 1) {      // in-wave suffix scan
        int u2 = __shfl_down(v, off);
        if (lane + off < 64) v += u2;
      }
      if (lane == 0) s_wsum[tid >> 6] = v;
    }
    __syncthreads();
    if (tid < 256) {
      int S = v;
      #pragma unroll
      for (int w = 0; w < 4; w++) if (w > (tid >> 6)) S += s_wsum[w];
      s_sfx[tid] = S;
    }
    __syncthreads();
    if (tid < 256) {
      int S = s_sfx[tid];
      int Snext = (tid == 255) ? 0 : s_sfx[tid + 1];
      if (S >= kk && Snext < kk) {                  // exactly one bin
        s_prefix = prefix | ((unsigned)tid << shift);
        s_kk = kk - Snext;
      }
    }
    __syncthreads();
    prefix = s_prefix; kk = s_kk;
    maskb |= 255u << shift;
    __syncthreads();
  }
  const float T = __uint_as_float(prefix);

  float sum_gt = 0.0f; int cnt_gt = 0;
  #pragma unroll
  for (int s9 = 0; s9 < 9; s9++) {
    const int p = tid + 1024 * s9;
    if (p < Pn) {
      float x = ce_r[s9];
      if (x > T) { sum_gt += x; cnt_gt++; }
    }
  }
  #pragma unroll
  for (int off = 32; off; off >>= 1) {
    sum_gt += __shfl_down(sum_gt, off);
    cnt_gt += __shfl_down(cnt_gt, off);
    my_loc += __shfl_down(my_loc, off);
    my_cep += __shfl_down(my_cep, off);
  }
  if (lane == 0) {
    s_redf[0][wv] = my_loc;
    s_redf[1][wv] = sum_gt + my_cep;
    s_redi[wv] = cnt_gt;
  }
  __syncthreads();
  if (tid == 0) {
    float ll = 0.0f, lc = 0.0f; int cg = 0;
    #pragma unroll
    for (int w = 0; w < 16; w++) {
      ll += s_redf[0][w]; lc += s_redf[1][w]; cg += s_redi[w];
    }
    if (k > 0) lc += (float)(k - cg) * T;
    atomicExch(&res[b * 4 + 0], __float_as_uint(ll));
    atomicExch(&res[b * 4 + 1], __float_as_uint(lc));
    atomicExch(&res[b * 4 + 2], (unsigned)s_np);
    __threadfence();
    atomicExch(&res[b * 4 + 3], MAGIC);
  }

  // ---- Phase E: block 0 gathers all 128 partials (all blocks co-resident)
  if (b == 0 && tid < 64) {
    float ll = 0.0f, lc = 0.0f; int np = 0;
    #pragma unroll
    for (int h = 0; h < 2; h++) {
      const int i = tid + 64 * h;
      while (atomicAdd(&res[i * 4 + 3], 0u) != MAGIC) { __builtin_amdgcn_s_sleep(8); }
      ll += __uint_as_float(atomicAdd(&res[i * 4 + 0], 0u));
      lc += __uint_as_float(atomicAdd(&res[i * 4 + 1], 0u));
      np += (int)atomicAdd(&res[i * 4 + 2], 0u);
    }
    #pragma unroll
    for (int off = 32; off; off >>= 1) {
      ll += __shfl_down(ll, off);
      lc += __shfl_down(lc, off);
      np += __shfl_down(np, off);
    }
    if (tid == 0) {
      float fN = (float)np;
      out[0] = ll / fN;
      out[1] = lc / fN;
    }
  }
}

extern "C" void kernel_launch(void* const* d_in, const int* in_sizes, int n_in,
                              void* d_out, int out_size, void* d_ws, size_t ws_size,
                              hipStream_t stream) {
  const float* loc_data  = (const float*)d_in[0];
  const float* conf_data = (const float*)d_in[1];
  const float* dbox      = (const float*)d_in[2];
  const float* targets   = (const float*)d_in[3];
  float* out = (float*)d_out;
  unsigned int* res = (unsigned int*)d_ws;   // 128*4 u32; flag beats 0xAA poison

  fused_kernel<<<Bn, 1024, 0, stream>>>(loc_data, conf_data, dbox, targets, res, out);
}

// Round 6
// 284.196 us; speedup vs baseline: 1.0851x; 1.0851x over previous
//
#include <hip/hip_runtime.h>
#include <cstddef>

#define Bn 128
#define Pn 8732
#define Cn 21
#define On 16
#define MAGIC 0x13579BDFu

__device__ __forceinline__ void argmax_combine(float& v, int& p, float v2, int p2) {
  if (v2 > v || (v2 == v && p2 < p)) { v = v2; p = p2; }
}

// ---------------------------------------------------------------------------
// One block per image (128 blocks x 1024 thr, 1 block/CU via ~150KB LDS).
// Phase B: 16 waves stream 137 chunks of 64 priors; register ping-pong
//   prefetch (COMPILE-TIME unrolled -> stays in VGPRs, no scratch!) hides HBM
//   latency behind softmax+IoU compute; ce0/bti -> LDS.
// Phase C: forced matches, losses (ce_neg in registers).
// Phase D: exact radix top-k with parallel shuffle suffix-scan.
// Phase E: atomicExch+flag handoff; block 0 finalizes (no extra node).
// ---------------------------------------------------------------------------
__global__ __launch_bounds__(1024) void fused_kernel(
    const float* __restrict__ loc, const float* __restrict__ conf,
    const float* __restrict__ dbox, const float* __restrict__ targets,
    unsigned int* __restrict__ res, float* __restrict__ out) {
  const int b = blockIdx.x;
  const int tid = threadIdx.x;
  const int wv = tid >> 6, lane = tid & 63;

  __shared__ float s_ce[Pn];              // ce0 per prior
  __shared__ float s_stage[16][1344];     // per-wave staging (5376 B each)
  __shared__ unsigned char s_bti[Pn];     // bti | pos<<4
  __shared__ unsigned hist[16][256];
  __shared__ float s_tt[80];
  __shared__ float s_ar[On];
  __shared__ float s_mv[On][16];
  __shared__ int   s_mp[On][16];
  __shared__ int   s_bp[On];
  __shared__ float s_redf[2][16];
  __shared__ int   s_redi[16];
  __shared__ int   s_sfx[256];
  __shared__ int   s_wsum[4];
  __shared__ unsigned s_prefix;
  __shared__ int s_kk, s_np;

  if (tid < 80) s_tt[tid] = targets[b * 80 + tid];
  __syncthreads();
  if (tid < On)
    s_ar[tid] = (s_tt[tid*5+2] - s_tt[tid*5+0]) * (s_tt[tid*5+3] - s_tt[tid*5+1]);
  __syncthreads();

  // ---- Phase B: stream conf (chunks ci = wv + 16*i), prefetch-pipelined ----
  float bestv[On]; int bestp[On];
  #pragma unroll
  for (int j = 0; j < On; j++) { bestv[j] = -1.0f; bestp[j] = 0x7fffffff; }

  const size_t confBase = (size_t)b * Pn * Cn;
  float4 rg[2][6];

  // chunk 0 prefetch (ci = wv <= 15 < 136 -> full chunk, no predication)
  {
    const float4* src = (const float4*)(conf + confBase + (size_t)wv * 64 * Cn);
    #pragma unroll
    for (int q = 0; q < 6; q++)
      if (lane + 64*q < 336) rg[0][q] = src[lane + 64*q];
  }

  #pragma unroll
  for (int i = 0; i < 9; i++) {                    // COMPILE-TIME trip count
    const int ci = wv + 16 * i;
    if (ci <= 136) {
      const int n4 = (ci == 136) ? 147 : 336;
      const int rows = (ci == 136) ? 28 : 64;

      {  // drain current chunk regs -> LDS (static index i&1 -> VGPRs)
        float4* dst = (float4*)s_stage[wv];
        #pragma unroll
        for (int q = 0; q < 6; q++)
          if (lane + 64*q < n4) dst[lane + 64*q] = rg[i & 1][q];
      }
      const int cn = ci + 16;
      if (cn <= 136) {                             // prefetch next, overlaps compute
        const int m4 = (cn == 136) ? 147 : 336;
        const float4* src = (const float4*)(conf + confBase + (size_t)cn * 64 * Cn);
        #pragma unroll
        for (int q = 0; q < 6; q++)
          if (lane + 64*q < m4) rg[(i + 1) & 1][q] = src[lane + 64*q];
      }

      if (lane < rows) {
        const int p = ci * 64 + lane;
        const float* x = s_stage[wv] + lane * Cn;  // stride-21: 2-way, free
        float m = x[0];
        #pragma unroll
        for (int q = 1; q < Cn; q++) m = fmaxf(m, x[q]);
        float s = 0.0f;
        #pragma unroll
        for (int q = 0; q < Cn; q++) s += expf(x[q] - m);
        float lse = m + logf(s);
        s_ce[p] = lse - x[0];                      // >= 0 always

        float4 d = ((const float4*)dbox)[p];
        float px1 = d.x - d.z * 0.5f, py1 = d.y - d.w * 0.5f;
        float px2 = d.x + d.z * 0.5f, py2 = d.y + d.w * 0.5f;
        float ap = d.z * d.w;
        float mv = -1.0f; int mj = 0;
        #pragma unroll
        for (int j = 0; j < On; j++) {
          float lx = fmaxf(s_tt[j*5+0], px1);
          float ly = fmaxf(s_tt[j*5+1], py1);
          float rx = fminf(s_tt[j*5+2], px2);
          float ry = fminf(s_tt[j*5+3], py2);
          float w = fmaxf(rx - lx, 0.0f), h = fmaxf(ry - ly, 0.0f);
          float inter = w * h;
          float ov = inter / (s_ar[j] + ap - inter);
          if (ov > bestv[j]) { bestv[j] = ov; bestp[j] = p; }  // smallest p kept
          if (ov > mv) { mv = ov; mj = j; }                    // first max over j
        }
        s_bti[p] = (unsigned char)(mj | ((mv >= 0.5f) ? 16 : 0));
      }
    }
  }

  // per-truth argmax: wave reduce -> LDS -> combine -> forced overwrites
  #pragma unroll
  for (int j = 0; j < On; j++) {
    float v = bestv[j]; int p = bestp[j];
    #pragma unroll
    for (int off = 32; off; off >>= 1) {
      float v2 = __shfl_down(v, off);
      int p2 = __shfl_down(p, off);
      argmax_combine(v, p, v2, p2);
    }
    if (lane == 0) { s_mv[j][wv] = v; s_mp[j][wv] = p; }
  }
  __syncthreads();
  if (tid < On) {
    float v = s_mv[tid][0]; int p = s_mp[tid][0];
    #pragma unroll
    for (int w = 1; w < 16; w++) argmax_combine(v, p, s_mv[tid][w], s_mp[tid][w]);
    s_bp[tid] = p;
  }
  __syncthreads();
  if (tid == 0) {
    #pragma unroll
    for (int j = 0; j < On; j++)                 // ascending: last j wins
      s_bti[s_bp[j]] = (unsigned char)(j | 16);
  }
  __syncthreads();

  // ---- Phase C: ce_neg to registers, np count, positive losses ----
  float ce_r[9];
  float my_loc = 0.0f, my_cep = 0.0f; int my_np = 0;
  #pragma unroll
  for (int s9 = 0; s9 < 9; s9++) {
    ce_r[s9] = 0.0f;
    const int p = tid + 1024 * s9;
    if (p < Pn) {
      int pk = s_bti[p];
      float c0 = s_ce[p];
      int pos = pk >> 4, bt = pk & 15;
      ce_r[s9] = pos ? 0.0f : c0;
      if (pos) {
        my_np++;
        const float* t = &s_tt[bt * 5];
        int c = (int)t[4] + 1;
        const float* row = conf + confBase + (size_t)p * Cn;
        my_cep += c0 + row[0] - row[c];            // lse - x[c]
        float4 d = ((const float4*)dbox)[p];
        float mx1 = t[0], my1 = t[1], mx2 = t[2], my2 = t[3];
        float g0 = ((mx1 + mx2) * 0.5f - d.x) / (0.1f * d.z);
        float g1 = ((my1 + my2) * 0.5f - d.y) / (0.1f * d.w);
        float g2 = logf((mx2 - mx1) / d.z) / 0.2f;
        float g3 = logf((my2 - my1) / d.w) / 0.2f;
        float4 ld = ((const float4*)loc)[(size_t)b * Pn + p];
        float g[4] = {g0, g1, g2, g3};
        float l[4] = {ld.x, ld.y, ld.z, ld.w};
        #pragma unroll
        for (int q = 0; q < 4; q++) {
          float ad = fabsf(l[q] - g[q]);
          my_loc += (ad < 1.0f) ? 0.5f * ad * ad : ad - 0.5f;
        }
      }
    }
  }
  {
    int np = my_np;
    #pragma unroll
    for (int off = 32; off; off >>= 1) np += __shfl_down(np, off);
    if (lane == 0) s_redi[wv] = np;
  }
  __syncthreads();
  if (tid == 0) {
    int np = 0;
    #pragma unroll
    for (int w = 0; w < 16; w++) np += s_redi[w];
    s_np = np;
  }
  __syncthreads();

  // ---- Phase D: exact k-th largest via radix select + parallel suffix scan
  const int k = min(s_np * 3, Pn);
  int kk = max(k, 1);                       // kk=1 degenerate: T=max, sel=0
  unsigned prefix = 0, maskb = 0;
  for (int shift = 24; shift >= 0; shift -= 8) {
    #pragma unroll
    for (int j = 0; j < 4; j++) hist[wv][lane * 4 + j] = 0;
    __syncthreads();
    #pragma unroll
    for (int s9 = 0; s9 < 9; s9++) {
      const int p = tid + 1024 * s9;
      if (p < Pn) {
        unsigned u = __float_as_uint(ce_r[s9]);
        if ((u & maskb) == prefix) atomicAdd(&hist[wv][(u >> shift) & 255u], 1u);
      }
    }
    __syncthreads();
    int v = 0;
    if (tid < 256) {
      int h = 0;
      #pragma unroll
      for (int w = 0; w < 16; w++) h += (int)hist[w][tid];
      v = h;
      #pragma unroll
      for (int off = 1; off < 64; off <<= 1) {      // in-wave suffix scan
        int u2 = __shfl_down(v, off);
        if (lane + off < 64) v += u2;
      }
      if (lane == 0) s_wsum[tid >> 6] = v;
    }
    __syncthreads();
    if (tid < 256) {
      int S = v;
      #pragma unroll
      for (int w = 0; w < 4; w++) if (w > (tid >> 6)) S += s_wsum[w];
      s_sfx[tid] = S;
    }
    __syncthreads();
    if (tid < 256) {
      int S = s_sfx[tid];
      int Snext = (tid == 255) ? 0 : s_sfx[tid + 1];
      if (S >= kk && Snext < kk) {                  // exactly one bin
        s_prefix = prefix | ((unsigned)tid << shift);
        s_kk = kk - Snext;
      }
    }
    __syncthreads();
    prefix = s_prefix; kk = s_kk;
    maskb |= 255u << shift;
    __syncthreads();
  }
  const float T = __uint_as_float(prefix);

  float sum_gt = 0.0f; int cnt_gt = 0;
  #pragma unroll
  for (int s9 = 0; s9 < 9; s9++) {
    const int p = tid + 1024 * s9;
    if (p < Pn) {
      float x = ce_r[s9];
      if (x > T) { sum_gt += x; cnt_gt++; }
    }
  }
  #pragma unroll
  for (int off = 32; off; off >>= 1) {
    sum_gt += __shfl_down(sum_gt, off);
    cnt_gt += __shfl_down(cnt_gt, off);
    my_loc += __shfl_down(my_loc, off);
    my_cep += __shfl_down(my_cep, off);
  }
  if (lane == 0) {
    s_redf[0][wv] = my_loc;
    s_redf[1][wv] = sum_gt + my_cep;
    s_redi[wv] = cnt_gt;
  }
  __syncthreads();
  if (tid == 0) {
    float ll = 0.0f, lc = 0.0f; int cg = 0;
    #pragma unroll
    for (int w = 0; w < 16; w++) {
      ll += s_redf[0][w]; lc += s_redf[1][w]; cg += s_redi[w];
    }
    if (k > 0) lc += (float)(k - cg) * T;
    atomicExch(&res[b * 4 + 0], __float_as_uint(ll));
    atomicExch(&res[b * 4 + 1], __float_as_uint(lc));
    atomicExch(&res[b * 4 + 2], (unsigned)s_np);
    __threadfence();
    atomicExch(&res[b * 4 + 3], MAGIC);
  }

  // ---- Phase E: block 0 gathers all 128 partials (all blocks co-resident)
  if (b == 0 && tid < 64) {
    float ll = 0.0f, lc = 0.0f; int np = 0;
    #pragma unroll
    for (int h = 0; h < 2; h++) {
      const int i = tid + 64 * h;
      while (atomicAdd(&res[i * 4 + 3], 0u) != MAGIC) { __builtin_amdgcn_s_sleep(8); }
      ll += __uint_as_float(atomicAdd(&res[i * 4 + 0], 0u));
      lc += __uint_as_float(atomicAdd(&res[i * 4 + 1], 0u));
      np += (int)atomicAdd(&res[i * 4 + 2], 0u);
    }
    #pragma unroll
    for (int off = 32; off; off >>= 1) {
      ll += __shfl_down(ll, off);
      lc += __shfl_down(lc, off);
      np += __shfl_down(np, off);
    }
    if (tid == 0) {
      float fN = (float)np;
      out[0] = ll / fN;
      out[1] = lc / fN;
    }
  }
}

extern "C" void kernel_launch(void* const* d_in, const int* in_sizes, int n_in,
                              void* d_out, int out_size, void* d_ws, size_t ws_size,
                              hipStream_t stream) {
  const float* loc_data  = (const float*)d_in[0];
  const float* conf_data = (const float*)d_in[1];
  const float* dbox      = (const float*)d_in[2];
  const float* targets   = (const float*)d_in[3];
  float* out = (float*)d_out;
  unsigned int* res = (unsigned int*)d_ws;   // 128*4 u32; flag beats 0xAA poison

  fused_kernel<<<Bn, 1024, 0, stream>>>(loc_data, conf_data, dbox, targets, res, out);
}

// Round 7
// 242.263 us; speedup vs baseline: 1.2729x; 1.1731x over previous
//
#include <hip/hip_runtime.h>
#include <cstddef>

#define Bn 128
#define Pn 8732
#define Cn 21
#define On 16
#define MAGIC 0x13579BDFu

__device__ __forceinline__ void argmax_combine(float& v, int& p, float v2, int p2) {
  if (v2 > v || (v2 == v && p2 < p)) { v = v2; p = p2; }
}

// ---------------------------------------------------------------------------
// One block per image (128 blocks x 1024 thr; 150KB LDS -> 1 block/CU;
// __launch_bounds__(1024,4) -> 16 waves/CU -> 128-VGPR budget, NO scratch).
// Phase B: 16 waves stream 137 chunks of 64 priors. Software pipeline over
//   NAMED float4 regs A0..A5 / B0..B5, macro-expanded (no dynamic indexing):
//   store cur->LDS, prefetch next->regs, compute softmax+IoU from LDS.
//   Stages 0..7 are full chunks for every wave (wv+112 <= 127); stage 8
//   (wv<=8 only) handles the partial chunk 136 (28 rows).
// Phase C: forced matches, losses (ce_neg in registers).
// Phase D: exact radix top-k with parallel shuffle suffix-scan.
// Phase E: atomicExch+flag handoff; block 0 finalizes (single graph node).
// ---------------------------------------------------------------------------
__global__ __launch_bounds__(1024, 4) void fused_kernel(
    const float* __restrict__ loc, const float* __restrict__ conf,
    const float* __restrict__ dbox, const float* __restrict__ targets,
    unsigned int* __restrict__ res, float* __restrict__ out) {
  const int b = blockIdx.x;
  const int tid = threadIdx.x;
  const int wv = tid >> 6, lane = tid & 63;

  __shared__ float s_ce[Pn];              // ce0 per prior
  __shared__ float s_stage[16][1344];     // per-wave staging (5376 B each)
  __shared__ unsigned char s_bti[Pn];     // bti | pos<<4
  __shared__ unsigned hist[16][256];
  __shared__ float s_tt[80];
  __shared__ float s_ar[On];
  __shared__ float s_mv[On][16];
  __shared__ int   s_mp[On][16];
  __shared__ int   s_bp[On];
  __shared__ float s_redf[2][16];
  __shared__ int   s_redi[16];
  __shared__ int   s_sfx[256];
  __shared__ int   s_wsum[4];
  __shared__ unsigned s_prefix;
  __shared__ int s_kk, s_np;

  if (tid < 80) s_tt[tid] = targets[b * 80 + tid];
  __syncthreads();
  if (tid < On)
    s_ar[tid] = (s_tt[tid*5+2] - s_tt[tid*5+0]) * (s_tt[tid*5+3] - s_tt[tid*5+1]);
  __syncthreads();

  // ---- Phase B ----
  float bestv[On]; int bestp[On];
  #pragma unroll
  for (int j = 0; j < On; j++) { bestv[j] = -1.0f; bestp[j] = 0x7fffffff; }

  const size_t confBase = (size_t)b * Pn * Cn;

#define LOADC(r0,r1,r2,r3,r4,r5, CI, N4) do {                                  \
    const float4* _s = (const float4*)(conf + confBase + (size_t)(CI)*(64*Cn));\
    if (lane       < (N4)) r0 = _s[lane];                                      \
    if (lane +  64 < (N4)) r1 = _s[lane +  64];                                \
    if (lane + 128 < (N4)) r2 = _s[lane + 128];                                \
    if (lane + 192 < (N4)) r3 = _s[lane + 192];                                \
    if (lane + 256 < (N4)) r4 = _s[lane + 256];                                \
    if (lane + 320 < (N4)) r5 = _s[lane + 320];                                \
  } while (0)

#define STOREC(r0,r1,r2,r3,r4,r5, N4) do {                                     \
    float4* _d = (float4*)s_stage[wv];                                         \
    if (lane       < (N4)) _d[lane]       = r0;                                \
    if (lane +  64 < (N4)) _d[lane +  64] = r1;                                \
    if (lane + 128 < (N4)) _d[lane + 128] = r2;                                \
    if (lane + 192 < (N4)) _d[lane + 192] = r3;                                \
    if (lane + 256 < (N4)) _d[lane + 256] = r4;                                \
    if (lane + 320 < (N4)) _d[lane + 320] = r5;                                \
  } while (0)

#define COMPUTEC(CI, ROWS) do {                                                \
    if (lane < (ROWS)) {                                                       \
      const int p = (CI) * 64 + lane;                                          \
      const float* x = s_stage[wv] + lane * Cn;                                \
      float m = x[0];                                                          \
      _Pragma("unroll")                                                        \
      for (int q = 1; q < Cn; q++) m = fmaxf(m, x[q]);                         \
      float s = 0.0f;                                                          \
      _Pragma("unroll")                                                        \
      for (int q = 0; q < Cn; q++) s += expf(x[q] - m);                        \
      float lse = m + logf(s);                                                 \
      s_ce[p] = lse - x[0];                                                    \
      float4 d = ((const float4*)dbox)[p];                                     \
      float px1 = d.x - d.z * 0.5f, py1 = d.y - d.w * 0.5f;                    \
      float px2 = d.x + d.z * 0.5f, py2 = d.y + d.w * 0.5f;                    \
      float ap = d.z * d.w;                                                    \
      float mv = -1.0f; int mj = 0;                                            \
      _Pragma("unroll")                                                        \
      for (int j = 0; j < On; j++) {                                           \
        float lx = fmaxf(s_tt[j*5+0], px1);                                    \
        float ly = fmaxf(s_tt[j*5+1], py1);                                    \
        float rx = fminf(s_tt[j*5+2], px2);                                    \
        float ry = fminf(s_tt[j*5+3], py2);                                    \
        float w = fmaxf(rx - lx, 0.0f), h = fmaxf(ry - ly, 0.0f);              \
        float inter = w * h;                                                   \
        float ov = inter / (s_ar[j] + ap - inter);                             \
        if (ov > bestv[j]) { bestv[j] = ov; bestp[j] = p; }                    \
        if (ov > mv) { mv = ov; mj = j; }                                      \
      }                                                                        \
      s_bti[p] = (unsigned char)(mj | ((mv >= 0.5f) ? 16 : 0));                \
    }                                                                          \
  } while (0)

  {
    float4 A0, A1, A2, A3, A4, A5, B0, B1, B2, B3, B4, B5;
    LOADC(A0,A1,A2,A3,A4,A5, wv, 336);

    STOREC(A0,A1,A2,A3,A4,A5, 336); LOADC(B0,B1,B2,B3,B4,B5, wv +  16, 336); COMPUTEC(wv,       64);
    STOREC(B0,B1,B2,B3,B4,B5, 336); LOADC(A0,A1,A2,A3,A4,A5, wv +  32, 336); COMPUTEC(wv +  16, 64);
    STOREC(A0,A1,A2,A3,A4,A5, 336); LOADC(B0,B1,B2,B3,B4,B5, wv +  48, 336); COMPUTEC(wv +  32, 64);
    STOREC(B0,B1,B2,B3,B4,B5, 336); LOADC(A0,A1,A2,A3,A4,A5, wv +  64, 336); COMPUTEC(wv +  48, 64);
    STOREC(A0,A1,A2,A3,A4,A5, 336); LOADC(B0,B1,B2,B3,B4,B5, wv +  80, 336); COMPUTEC(wv +  64, 64);
    STOREC(B0,B1,B2,B3,B4,B5, 336); LOADC(A0,A1,A2,A3,A4,A5, wv +  96, 336); COMPUTEC(wv +  80, 64);
    STOREC(A0,A1,A2,A3,A4,A5, 336); LOADC(B0,B1,B2,B3,B4,B5, wv + 112, 336); COMPUTEC(wv +  96, 64);
    {
      const int n4_last = (wv == 8) ? 147 : 336;          // chunk wv+128 size
      STOREC(B0,B1,B2,B3,B4,B5, 336);
      if (wv <= 8) LOADC(A0,A1,A2,A3,A4,A5, wv + 128, n4_last);
      COMPUTEC(wv + 112, 64);
    }
    if (wv <= 8) {                                        // stage 8: last chunk
      const int n4_last = (wv == 8) ? 147 : 336;
      const int rows_last = (wv == 8) ? 28 : 64;
      STOREC(A0,A1,A2,A3,A4,A5, n4_last);
      COMPUTEC(wv + 128, rows_last);
    }
  }
#undef LOADC
#undef STOREC
#undef COMPUTEC

  // per-truth argmax: wave reduce -> LDS -> combine -> forced overwrites
  #pragma unroll
  for (int j = 0; j < On; j++) {
    float v = bestv[j]; int p = bestp[j];
    #pragma unroll
    for (int off = 32; off; off >>= 1) {
      float v2 = __shfl_down(v, off);
      int p2 = __shfl_down(p, off);
      argmax_combine(v, p, v2, p2);
    }
    if (lane == 0) { s_mv[j][wv] = v; s_mp[j][wv] = p; }
  }
  __syncthreads();
  if (tid < On) {
    float v = s_mv[tid][0]; int p = s_mp[tid][0];
    #pragma unroll
    for (int w = 1; w < 16; w++) argmax_combine(v, p, s_mv[tid][w], s_mp[tid][w]);
    s_bp[tid] = p;
  }
  __syncthreads();
  if (tid == 0) {
    #pragma unroll
    for (int j = 0; j < On; j++)                 // ascending: last j wins
      s_bti[s_bp[j]] = (unsigned char)(j | 16);
  }
  __syncthreads();

  // ---- Phase C: ce_neg to registers, np count, positive losses ----
  float ce_r[9];
  float my_loc = 0.0f, my_cep = 0.0f; int my_np = 0;
  #pragma unroll
  for (int s9 = 0; s9 < 9; s9++) {
    ce_r[s9] = 0.0f;
    const int p = tid + 1024 * s9;
    if (p < Pn) {
      int pk = s_bti[p];
      float c0 = s_ce[p];
      int pos = pk >> 4, bt = pk & 15;
      ce_r[s9] = pos ? 0.0f : c0;
      if (pos) {
        my_np++;
        const float* t = &s_tt[bt * 5];
        int c = (int)t[4] + 1;
        const float* row = conf + confBase + (size_t)p * Cn;
        my_cep += c0 + row[0] - row[c];            // lse - x[c]
        float4 d = ((const float4*)dbox)[p];
        float mx1 = t[0], my1 = t[1], mx2 = t[2], my2 = t[3];
        float g0 = ((mx1 + mx2) * 0.5f - d.x) / (0.1f * d.z);
        float g1 = ((my1 + my2) * 0.5f - d.y) / (0.1f * d.w);
        float g2 = logf((mx2 - mx1) / d.z) / 0.2f;
        float g3 = logf((my2 - my1) / d.w) / 0.2f;
        float4 ld = ((const float4*)loc)[(size_t)b * Pn + p];
        float g[4] = {g0, g1, g2, g3};
        float l[4] = {ld.x, ld.y, ld.z, ld.w};
        #pragma unroll
        for (int q = 0; q < 4; q++) {
          float ad = fabsf(l[q] - g[q]);
          my_loc += (ad < 1.0f) ? 0.5f * ad * ad : ad - 0.5f;
        }
      }
    }
  }
  {
    int np = my_np;
    #pragma unroll
    for (int off = 32; off; off >>= 1) np += __shfl_down(np, off);
    if (lane == 0) s_redi[wv] = np;
  }
  __syncthreads();
  if (tid == 0) {
    int np = 0;
    #pragma unroll
    for (int w = 0; w < 16; w++) np += s_redi[w];
    s_np = np;
  }
  __syncthreads();

  // ---- Phase D: exact k-th largest via radix select + parallel suffix scan
  const int k = min(s_np * 3, Pn);
  int kk = max(k, 1);                       // kk=1 degenerate: T=max, sel=0
  unsigned prefix = 0, maskb = 0;
  for (int shift = 24; shift >= 0; shift -= 8) {
    #pragma unroll
    for (int j = 0; j < 4; j++) hist[wv][lane * 4 + j] = 0;
    __syncthreads();
    #pragma unroll
    for (int s9 = 0; s9 < 9; s9++) {
      const int p = tid + 1024 * s9;
      if (p < Pn) {
        unsigned u = __float_as_uint(ce_r[s9]);
        if ((u & maskb) == prefix) atomicAdd(&hist[wv][(u >> shift) & 255u], 1u);
      }
    }
    __syncthreads();
    int v = 0;
    if (tid < 256) {
      int h = 0;
      #pragma unroll
      for (int w = 0; w < 16; w++) h += (int)hist[w][tid];
      v = h;
      #pragma unroll
      for (int off = 1; off < 64; off <<= 1) {      // in-wave suffix scan
        int u2 = __shfl_down(v, off);
        if (lane + off < 64) v += u2;
      }
      if (lane == 0) s_wsum[tid >> 6] = v;
    }
    __syncthreads();
    if (tid < 256) {
      int S = v;
      #pragma unroll
      for (int w = 0; w < 4; w++) if (w > (tid >> 6)) S += s_wsum[w];
      s_sfx[tid] = S;
    }
    __syncthreads();
    if (tid < 256) {
      int S = s_sfx[tid];
      int Snext = (tid == 255) ? 0 : s_sfx[tid + 1];
      if (S >= kk && Snext < kk) {                  // exactly one bin
        s_prefix = prefix | ((unsigned)tid << shift);
        s_kk = kk - Snext;
      }
    }
    __syncthreads();
    prefix = s_prefix; kk = s_kk;
    maskb |= 255u << shift;
    __syncthreads();
  }
  const float T = __uint_as_float(prefix);

  float sum_gt = 0.0f; int cnt_gt = 0;
  #pragma unroll
  for (int s9 = 0; s9 < 9; s9++) {
    const int p = tid + 1024 * s9;
    if (p < Pn) {
      float x = ce_r[s9];
      if (x > T) { sum_gt += x; cnt_gt++; }
    }
  }
  #pragma unroll
  for (int off = 32; off; off >>= 1) {
    sum_gt += __shfl_down(sum_gt, off);
    cnt_gt += __shfl_down(cnt_gt, off);
    my_loc += __shfl_down(my_loc, off);
    my_cep += __shfl_down(my_cep, off);
  }
  if (lane == 0) {
    s_redf[0][wv] = my_loc;
    s_redf[1][wv] = sum_gt + my_cep;
    s_redi[wv] = cnt_gt;
  }
  __syncthreads();
  if (tid == 0) {
    float ll = 0.0f, lc = 0.0f; int cg = 0;
    #pragma unroll
    for (int w = 0; w < 16; w++) {
      ll += s_redf[0][w]; lc += s_redf[1][w]; cg += s_redi[w];
    }
    if (k > 0) lc += (float)(k - cg) * T;
    atomicExch(&res[b * 4 + 0], __float_as_uint(ll));
    atomicExch(&res[b * 4 + 1], __float_as_uint(lc));
    atomicExch(&res[b * 4 + 2], (unsigned)s_np);
    __threadfence();
    atomicExch(&res[b * 4 + 3], MAGIC);
  }

  // ---- Phase E: block 0 gathers all 128 partials (all blocks co-resident)
  if (b == 0 && tid < 64) {
    float ll = 0.0f, lc = 0.0f; int np = 0;
    #pragma unroll
    for (int h = 0; h < 2; h++) {
      const int i = tid + 64 * h;
      while (atomicAdd(&res[i * 4 + 3], 0u) != MAGIC) { __builtin_amdgcn_s_sleep(8); }
      ll += __uint_as_float(atomicAdd(&res[i * 4 + 0], 0u));
      lc += __uint_as_float(atomicAdd(&res[i * 4 + 1], 0u));
      np += (int)atomicAdd(&res[i * 4 + 2], 0u);
    }
    #pragma unroll
    for (int off = 32; off; off >>= 1) {
      ll += __shfl_down(ll, off);
      lc += __shfl_down(lc, off);
      np += __shfl_down(np, off);
    }
    if (tid == 0) {
      float fN = (float)np;
      out[0] = ll / fN;
      out[1] = lc / fN;
    }
  }
}

extern "C" void kernel_launch(void* const* d_in, const int* in_sizes, int n_in,
                              void* d_out, int out_size, void* d_ws, size_t ws_size,
                              hipStream_t stream) {
  const float* loc_data  = (const float*)d_in[0];
  const float* conf_data = (const float*)d_in[1];
  const float* dbox      = (const float*)d_in[2];
  const float* targets   = (const float*)d_in[3];
  float* out = (float*)d_out;
  unsigned int* res = (unsigned int*)d_ws;   // 128*4 u32; flag beats 0xAA poison

  fused_kernel<<<Bn, 1024, 0, stream>>>(loc_data, conf_data, dbox, targets, res, out);
}

// Round 8
// 234.931 us; speedup vs baseline: 1.3127x; 1.0312x over previous
//
#include <hip/hip_runtime.h>
#include <cstddef>
#include <cstdint>

#define Bn 128
#define Pn 8732
#define Cn 21
#define On 16
#define MAGIC 0x13579BDFu

__device__ __forceinline__ void argmax_combine(float& v, int& p, float v2, int p2) {
  if (v2 > v || (v2 == v && p2 < p)) { v = v2; p = p2; }
}

// async 16B global -> LDS (wave-uniform LDS base; HW writes base + lane*16)
__device__ __forceinline__ void cp16_lds(const float4* g, float4* l) {
  __builtin_amdgcn_global_load_lds(
      (const __attribute__((address_space(1))) unsigned int*)g,
      (__attribute__((address_space(3))) unsigned int*)l, 16, 0, 0);
}

// ---------------------------------------------------------------------------
// One block per image (128 x 1024, ~150KB LDS -> 1 block/CU).
// Phase A: IoU matching (dbox+targets only; bestv/bestp regs die here).
// Phase B: conf streamed via global_load_lds (NO staging registers, no
//   scratch): per wave, chunks ci = wv+16i of 64 priors; 6 async 16B issues,
//   s_waitcnt vmcnt(0), softmax from LDS. Chunk 0 issued before Phase A so
//   its latency hides under matching VALU work.
// Phase C: forced matches + losses (ce_neg in registers).
// Phase D: exact radix top-k with parallel suffix scan.
// Phase E: atomicExch+flag handoff; block 0 finalizes (single graph node).
// ---------------------------------------------------------------------------
__global__ __launch_bounds__(1024) void fused_kernel(
    const float* __restrict__ loc, const float* __restrict__ conf,
    const float* __restrict__ dbox, const float* __restrict__ targets,
    unsigned int* __restrict__ res, float* __restrict__ out) {
  const int b = blockIdx.x;
  const int tid = threadIdx.x;
  const int wv = tid >> 6, lane = tid & 63;

  __shared__ float s_ce[Pn];              // ce0 per prior
  __shared__ float s_stage[16][1344];     // per-wave staging (5376 B each)
  __shared__ unsigned char s_bti[Pn];     // bti | pos<<4
  __shared__ unsigned hist[16][256];
  __shared__ float s_tt[80];
  __shared__ float s_ar[On];
  __shared__ float s_mv[On][16];
  __shared__ int   s_mp[On][16];
  __shared__ int   s_bp[On];
  __shared__ float s_redf[2][16];
  __shared__ int   s_redi[16];
  __shared__ int   s_sfx[256];
  __shared__ int   s_wsum[4];
  __shared__ unsigned s_prefix;
  __shared__ int s_kk, s_np;

  const size_t confBase = (size_t)b * Pn * Cn;

  // issue chunk `wv` of conf into this wave's slice (latency hides under A)
  {
    const float4* src = (const float4*)(conf + confBase + (size_t)wv * (64 * Cn));
    float4* dst = (float4*)s_stage[wv];
    #pragma unroll
    for (int q = 0; q < 6; q++)
      if (lane + 64 * q < 336) cp16_lds(src + lane + 64 * q, dst + 64 * q);
  }

  if (tid < 80) s_tt[tid] = targets[b * 80 + tid];
  __syncthreads();
  if (tid < On)
    s_ar[tid] = (s_tt[tid*5+2] - s_tt[tid*5+0]) * (s_tt[tid*5+3] - s_tt[tid*5+1]);
  __syncthreads();

  // ---- Phase A: matching (IoU), no conf needed ----
  {
    float bestv[On]; int bestp[On];
    #pragma unroll
    for (int j = 0; j < On; j++) { bestv[j] = -1.0f; bestp[j] = 0x7fffffff; }

    for (int p = tid; p < Pn; p += 1024) {
      float4 d = ((const float4*)dbox)[p];
      float px1 = d.x - d.z * 0.5f, py1 = d.y - d.w * 0.5f;
      float px2 = d.x + d.z * 0.5f, py2 = d.y + d.w * 0.5f;
      float ap = d.z * d.w;
      float mv = -1.0f; int mj = 0;
      #pragma unroll
      for (int j = 0; j < On; j++) {
        float lx = fmaxf(s_tt[j*5+0], px1);
        float ly = fmaxf(s_tt[j*5+1], py1);
        float rx = fminf(s_tt[j*5+2], px2);
        float ry = fminf(s_tt[j*5+3], py2);
        float w = fmaxf(rx - lx, 0.0f), h = fmaxf(ry - ly, 0.0f);
        float inter = w * h;
        float ov = inter / (s_ar[j] + ap - inter);
        if (ov > bestv[j]) { bestv[j] = ov; bestp[j] = p; }  // smallest p kept
        if (ov > mv) { mv = ov; mj = j; }                    // first max over j
      }
      s_bti[p] = (unsigned char)(mj | ((mv >= 0.5f) ? 16 : 0));
    }

    // per-wave argmax partials -> LDS (cross-wave combine deferred past B)
    #pragma unroll
    for (int j = 0; j < On; j++) {
      float v = bestv[j]; int p = bestp[j];
      #pragma unroll
      for (int off = 32; off; off >>= 1) {
        float v2 = __shfl_down(v, off);
        int p2 = __shfl_down(p, off);
        argmax_combine(v, p, v2, p2);
      }
      if (lane == 0) { s_mv[j][wv] = v; s_mp[j][wv] = p; }
    }
  }  // bestv/bestp dead here

  // ---- Phase B: stream conf chunks ci = wv + 16*i via global_load_lds ----
  for (int ci = wv; ci < 137; ci += 16) {
    asm volatile("s_waitcnt vmcnt(0)" ::: "memory");   // chunk ci landed in LDS
    const int rows = (ci == 136) ? 28 : 64;
    if (lane < rows) {
      const int p = ci * 64 + lane;
      const float* x = s_stage[wv] + lane * Cn;        // stride-21: 2-way, free
      float m = x[0];
      #pragma unroll
      for (int q = 1; q < Cn; q++) m = fmaxf(m, x[q]);
      float s = 0.0f;
      #pragma unroll
      for (int q = 0; q < Cn; q++) s += expf(x[q] - m);
      float lse = m + logf(s);
      s_ce[p] = lse - x[0];                            // >= 0 always
    }
    asm volatile("s_waitcnt lgkmcnt(0)" ::: "memory"); // slice reads done
    const int cn = ci + 16;
    if (cn < 137) {
      const int n4 = (cn == 136) ? 147 : 336;
      const float4* src = (const float4*)(conf + confBase + (size_t)cn * (64 * Cn));
      float4* dst = (float4*)s_stage[wv];
      #pragma unroll
      for (int q = 0; q < 6; q++)
        if (lane + 64 * q < n4) cp16_lds(src + lane + 64 * q, dst + 64 * q);
    }
  }
  __syncthreads();

  // cross-wave argmax combine + forced overwrites
  if (tid < On) {
    float v = s_mv[tid][0]; int p = s_mp[tid][0];
    #pragma unroll
    for (int w = 1; w < 16; w++) argmax_combine(v, p, s_mv[tid][w], s_mp[tid][w]);
    s_bp[tid] = p;
  }
  __syncthreads();
  if (tid == 0) {
    #pragma unroll
    for (int j = 0; j < On; j++)                 // ascending: last j wins
      s_bti[s_bp[j]] = (unsigned char)(j | 16);
  }
  __syncthreads();

  // ---- Phase C: ce_neg to registers, np count, positive losses ----
  float ce_r[9];
  float my_loc = 0.0f, my_cep = 0.0f; int my_np = 0;
  #pragma unroll
  for (int s9 = 0; s9 < 9; s9++) {
    ce_r[s9] = 0.0f;
    const int p = tid + 1024 * s9;
    if (p < Pn) {
      int pk = s_bti[p];
      float c0 = s_ce[p];
      int pos = pk >> 4, bt = pk & 15;
      ce_r[s9] = pos ? 0.0f : c0;
      if (pos) {
        my_np++;
        const float* t = &s_tt[bt * 5];
        int c = (int)t[4] + 1;
        const float* row = conf + confBase + (size_t)p * Cn;
        my_cep += c0 + row[0] - row[c];            // lse - x[c]
        float4 d = ((const float4*)dbox)[p];
        float mx1 = t[0], my1 = t[1], mx2 = t[2], my2 = t[3];
        float g0 = ((mx1 + mx2) * 0.5f - d.x) / (0.1f * d.z);
        float g1 = ((my1 + my2) * 0.5f - d.y) / (0.1f * d.w);
        float g2 = logf((mx2 - mx1) / d.z) / 0.2f;
        float g3 = logf((my2 - my1) / d.w) / 0.2f;
        float4 ld = ((const float4*)loc)[(size_t)b * Pn + p];
        float g[4] = {g0, g1, g2, g3};
        float l[4] = {ld.x, ld.y, ld.z, ld.w};
        #pragma unroll
        for (int q = 0; q < 4; q++) {
          float ad = fabsf(l[q] - g[q]);
          my_loc += (ad < 1.0f) ? 0.5f * ad * ad : ad - 0.5f;
        }
      }
    }
  }
  {
    int np = my_np;
    #pragma unroll
    for (int off = 32; off; off >>= 1) np += __shfl_down(np, off);
    if (lane == 0) s_redi[wv] = np;
  }
  __syncthreads();
  if (tid == 0) {
    int np = 0;
    #pragma unroll
    for (int w = 0; w < 16; w++) np += s_redi[w];
    s_np = np;
  }
  __syncthreads();

  // ---- Phase D: exact k-th largest via radix select + parallel suffix scan
  const int k = min(s_np * 3, Pn);
  int kk = max(k, 1);                       // kk=1 degenerate: T=max, sel=0
  unsigned prefix = 0, maskb = 0;
  for (int shift = 24; shift >= 0; shift -= 8) {
    #pragma unroll
    for (int j = 0; j < 4; j++) hist[wv][lane * 4 + j] = 0;
    __syncthreads();
    #pragma unroll
    for (int s9 = 0; s9 < 9; s9++) {
      const int p = tid + 1024 * s9;
      if (p < Pn) {
        unsigned u = __float_as_uint(ce_r[s9]);
        if ((u & maskb) == prefix) atomicAdd(&hist[wv][(u >> shift) & 255u], 1u);
      }
    }
    __syncthreads();
    int v = 0;
    if (tid < 256) {
      int h = 0;
      #pragma unroll
      for (int w = 0; w < 16; w++) h += (int)hist[w][tid];
      v = h;
      #pragma unroll
      for (int off = 1; off < 64; off <<= 1) {      // in-wave suffix scan
        int u2 = __shfl_down(v, off);
        if (lane + off < 64) v += u2;
      }
      if (lane == 0) s_wsum[tid >> 6] = v;
    }
    __syncthreads();
    if (tid < 256) {
      int S = v;
      #pragma unroll
      for (int w = 0; w < 4; w++) if (w > (tid >> 6)) S += s_wsum[w];
      s_sfx[tid] = S;
    }
    __syncthreads();
    if (tid < 256) {
      int S = s_sfx[tid];
      int Snext = (tid == 255) ? 0 : s_sfx[tid + 1];
      if (S >= kk && Snext < kk) {                  // exactly one bin
        s_prefix = prefix | ((unsigned)tid << shift);
        s_kk = kk - Snext;
      }
    }
    __syncthreads();
    prefix = s_prefix; kk = s_kk;
    maskb |= 255u << shift;
    __syncthreads();
  }
  const float T = __uint_as_float(prefix);

  float sum_gt = 0.0f; int cnt_gt = 0;
  #pragma unroll
  for (int s9 = 0; s9 < 9; s9++) {
    const int p = tid + 1024 * s9;
    if (p < Pn) {
      float x = ce_r[s9];
      if (x > T) { sum_gt += x; cnt_gt++; }
    }
  }
  #pragma unroll
  for (int off = 32; off; off >>= 1) {
    sum_gt += __shfl_down(sum_gt, off);
    cnt_gt += __shfl_down(cnt_gt, off);
    my_loc += __shfl_down(my_loc, off);
    my_cep += __shfl_down(my_cep, off);
  }
  if (lane == 0) {
    s_redf[0][wv] = my_loc;
    s_redf[1][wv] = sum_gt + my_cep;
    s_redi[wv] = cnt_gt;
  }
  __syncthreads();
  if (tid == 0) {
    float ll = 0.0f, lc = 0.0f; int cg = 0;
    #pragma unroll
    for (int w = 0; w < 16; w++) {
      ll += s_redf[0][w]; lc += s_redf[1][w]; cg += s_redi[w];
    }
    if (k > 0) lc += (float)(k - cg) * T;
    atomicExch(&res[b * 4 + 0], __float_as_uint(ll));
    atomicExch(&res[b * 4 + 1], __float_as_uint(lc));
    atomicExch(&res[b * 4 + 2], (unsigned)s_np);
    __threadfence();
    atomicExch(&res[b * 4 + 3], MAGIC);
  }

  // ---- Phase E: block 0 gathers all 128 partials (all blocks co-resident)
  if (b == 0 && tid < 64) {
    float ll = 0.0f, lc = 0.0f; int np = 0;
    #pragma unroll
    for (int h = 0; h < 2; h++) {
      const int i = tid + 64 * h;
      while (atomicAdd(&res[i * 4 + 3], 0u) != MAGIC) { __builtin_amdgcn_s_sleep(8); }
      ll += __uint_as_float(atomicAdd(&res[i * 4 + 0], 0u));
      lc += __uint_as_float(atomicAdd(&res[i * 4 + 1], 0u));
      np += (int)atomicAdd(&res[i * 4 + 2], 0u);
    }
    #pragma unroll
    for (int off = 32; off; off >>= 1) {
      ll += __shfl_down(ll, off);
      lc += __shfl_down(lc, off);
      np += __shfl_down(np, off);
    }
    if (tid == 0) {
      float fN = (float)np;
      out[0] = ll / fN;
      out[1] = lc / fN;
    }
  }
}

extern "C" void kernel_launch(void* const* d_in, const int* in_sizes, int n_in,
                              void* d_out, int out_size, void* d_ws, size_t ws_size,
                              hipStream_t stream) {
  const float* loc_data  = (const float*)d_in[0];
  const float* conf_data = (const float*)d_in[1];
  const float* dbox      = (const float*)d_in[2];
  const float* targets   = (const float*)d_in[3];
  float* out = (float*)d_out;
  unsigned int* res = (unsigned int*)d_ws;   // 128*4 u32; flag beats 0xAA poison

  fused_kernel<<<Bn, 1024, 0, stream>>>(loc_data, conf_data, dbox, targets, res, out);
}